// Round 5
// baseline (405.585 us; speedup 1.0000x reference)
//
#include <hip/hip_runtime.h>

// Problem constants (T=64, B=32, I=128, H=256, alpha=0.2)
#define TT 64
#define BB 32
#define II 128
#define HH 256
#define MM (TT*BB)   // 2048

typedef __bf16  bf16x8  __attribute__((ext_vector_type(8)));
typedef float   f32x16  __attribute__((ext_vector_type(16)));
typedef _Float16 half2v __attribute__((ext_vector_type(2)));

__device__ __forceinline__ float bf2f(unsigned short u) {
    union { unsigned int i; float f; } v; v.i = ((unsigned int)u) << 16; return v.f;
}
__device__ __forceinline__ unsigned short f2bf(float f) {
    union { float f; unsigned int i; } v; v.f = f;
    unsigned int r = v.i + 0x7fffu + ((v.i >> 16) & 1u);
    return (unsigned short)(r >> 16);
}

// Dual-dtype loaders: external tensors may be fp32 or bf16; runtime flag decides.
struct F8 { float v[8]; };
__device__ __forceinline__ F8 load8(const void* base, int idx, int isf32) {
    F8 r;
    if (isf32) {
        const float4* p = (const float4*)((const float*)base + idx);
        float4 a = p[0], b = p[1];
        r.v[0]=a.x; r.v[1]=a.y; r.v[2]=a.z; r.v[3]=a.w;
        r.v[4]=b.x; r.v[5]=b.y; r.v[6]=b.z; r.v[7]=b.w;
    } else {
        uint4 u = *(const uint4*)((const unsigned short*)base + idx);
        const unsigned short* p = (const unsigned short*)&u;
#pragma unroll
        for (int j = 0; j < 8; ++j) r.v[j] = bf2f(p[j]);
    }
    return r;
}
__device__ __forceinline__ float load1(const void* base, int idx, int isf32) {
    return isf32 ? ((const float*)base)[idx]
                 : bf2f(((const unsigned short*)base)[idx]);
}

__device__ __forceinline__ float fdot2f(half2v a, half2v b, float c) {
#if __has_builtin(__builtin_amdgcn_fdot2)
    return __builtin_amdgcn_fdot2(a, b, c, false);
#else
    return c + (float)a.x*(float)b.x + (float)a.y*(float)b.y;
#endif
}

// ---------------------------------------------------------------------------
// K0: dtype sniffer (fp32 read as ushorts -> ~25% have exponent >= 0xC0).
// ---------------------------------------------------------------------------
__global__ __launch_bounds__(256) void k0_sniff(
    const unsigned short* __restrict__ x, int* __restrict__ flag)
{
    __shared__ int cnt;
    if (threadIdx.x == 0) cnt = 0;
    __syncthreads();
    int c = 0;
    for (int i = threadIdx.x; i < 8192; i += 256) {
        unsigned int e = (x[i] >> 7) & 0xFFu;
        if (e >= 0xC0u) ++c;
    }
    atomicAdd(&cnt, c);
    __syncthreads();
    if (threadIdx.x == 0) flag[0] = (cnt > 16) ? 1 : 0;
}

// ---------------------------------------------------------------------------
// K1 v2 (unchanged): weights resident in VGPRs, 32 m per block.
// ---------------------------------------------------------------------------
__global__ __launch_bounds__(256) void k1_proj(
    const void* __restrict__ x,
    const void* __restrict__ w_i2h,
    const void* __restrict__ b_i2h,
    const void* __restrict__ w_i2c,
    const void* __restrict__ b_i2c,
    const int* __restrict__ flagp,
    unsigned short* __restrict__ ip,
    float* __restrict__ cin)
{
    const int isf32 = *flagp;
    const int tid = threadIdx.x;
    const int h = tid;
    const int mbase = blockIdx.x * 32;
    __shared__ __align__(16) _Float16 xs[32][II];   // 8 KB

    half2v w1[II/2], w2[II/2];
#pragma unroll
    for (int c8 = 0; c8 < II/8; ++c8) {
        F8 f1 = load8(w_i2h, h*II + c8*8, isf32);
        F8 f2 = load8(w_i2c, h*II + c8*8, isf32);
#pragma unroll
        for (int j = 0; j < 4; ++j) {
            half2v a; a.x = (_Float16)f1.v[2*j]; a.y = (_Float16)f1.v[2*j+1];
            half2v b; b.x = (_Float16)f2.v[2*j]; b.y = (_Float16)f2.v[2*j+1];
            w1[c8*4 + j] = a;
            w2[c8*4 + j] = b;
        }
    }
    const float bb1 = load1(b_i2h, h, isf32);
    const float bb2 = load1(b_i2c, h, isf32);

    for (int u = tid; u < 32*II; u += 256)
        xs[u >> 7][u & (II-1)] = (_Float16)load1(x, (mbase + (u >> 7))*II + (u & (II-1)), isf32);
    __syncthreads();

    for (int mm = 0; mm < 32; ++mm) {
        const half2v* xv = (const half2v*)xs[mm];
        float a0=0,a1=0,a2=0,a3=0, c0=0,c1=0,c2=0,c3=0;
#pragma unroll
        for (int r = 0; r < II/2; r += 4) {
            half2v x0 = xv[r], x1 = xv[r+1], x2 = xv[r+2], x3 = xv[r+3];
            a0 = fdot2f(w1[r],   x0, a0);
            a1 = fdot2f(w1[r+1], x1, a1);
            a2 = fdot2f(w1[r+2], x2, a2);
            a3 = fdot2f(w1[r+3], x3, a3);
            c0 = fdot2f(w2[r],   x0, c0);
            c1 = fdot2f(w2[r+1], x1, c1);
            c2 = fdot2f(w2[r+2], x2, c2);
            c3 = fdot2f(w2[r+3], x3, c3);
        }
        ip[(mbase+mm)*HH + h]  = f2bf(((a0+a1)+(a2+a3)) + bb1);
        cin[(mbase+mm)*HH + h] = ((c0+c1)+(c2+c3)) + bb2;
    }
}

// ---------------------------------------------------------------------------
// K2 v2 (unchanged): per-sample context chains, double-buffered LDS.
// ---------------------------------------------------------------------------
__global__ __launch_bounds__(256) void k2_ctx(
    const void* __restrict__ w_c2c,
    const void* __restrict__ b_c2c,
    const float* __restrict__ cin,
    const int* __restrict__ ns_ptr,
    const int* __restrict__ flagp,
    unsigned short* __restrict__ ctx_hist,
    void* __restrict__ out_base)
{
    const int isf32 = *flagp;
    const int b = blockIdx.x;
    const int h = threadIdx.x;
    const int ns = max(1, *ns_ptr);

    __shared__ __align__(16) _Float16 cs[2][HH];

    half2v w[HH/2];
#pragma unroll
    for (int c8 = 0; c8 < HH/8; ++c8) {
        F8 f = load8(w_c2c, h*HH + c8*8, isf32);
#pragma unroll
        for (int j = 0; j < 4; ++j) {
            half2v hv;
            hv.x = (_Float16)f.v[2*j];
            hv.y = (_Float16)f.v[2*j+1];
            w[c8*4 + j] = hv;
        }
    }
    const float bcc = load1(b_c2c, h, isf32);
    float ctxv = 0.0f;
    cs[0][h] = (_Float16)0.0f;
    __syncthreads();
    int cur = 0;

    for (int t = 0; t < TT; ++t) {
        const float cinv = cin[(t*BB + b)*HH + h];
        for (int s = 0; s < ns; ++s) {
            if (s == ns-1) ctx_hist[(t*BB + b)*HH + h] = f2bf(ctxv);
            float p0=0,p1=0,p2=0,p3=0;
            const float4* cp4 = (const float4*)cs[cur];   // 16B = 4 half2
#pragma unroll
            for (int r4 = 0; r4 < HH/8; ++r4) {
                float4 blob = cp4[r4];
                const half2v* c2 = (const half2v*)&blob;
                p0 = fdot2f(w[r4*4+0], c2[0], p0);
                p1 = fdot2f(w[r4*4+1], c2[1], p1);
                p2 = fdot2f(w[r4*4+2], c2[2], p2);
                p3 = fdot2f(w[r4*4+3], c2[3], p3);
            }
            float cnew = fmaxf(((p0+p1)+(p2+p3)) + bcc + cinv, 0.0f);
            ctxv = 0.8f*ctxv + 0.2f*cnew;
            cs[cur^1][h] = (_Float16)ctxv;
            cur ^= 1;
            __syncthreads();
        }
    }
    const int cofs = MM*HH + BB*HH + b*HH + h;
    if (isf32) ((float*)out_base)[cofs] = ctxv;
    else       ((unsigned short*)out_base)[cofs] = f2bf(ctxv);
}

// ---------------------------------------------------------------------------
// K3 v4: B-resident-in-LDS (131072 B) + A chunk (32768 B, overlaid by the
// 2x256-f32 partial buffer during the epilogue). One block per i, 512 thr.
// Changes vs v3:
//  - A chunk for the NEXT kc is prefetched into VGPRs during the MFMA loop
//    (hides L2 latency; barriers bracket only the ds_writes).
//  - Epilogue: in-register (acc+bc)*ip partials, 5x shfl_xor j-reduction,
//    tiny LDS partial merge of the two j-half waves. 10 barriers/mc (was 24),
//    no TM LDS round-trip.
//  - Stores go to outT[i][m] (contiguous) in workspace; k4 transposes.
// ---------------------------------------------------------------------------
__global__ __launch_bounds__(512, 1) void k3_main(
    const unsigned short* __restrict__ ctx_hist,  // [2048,256] bf16 (internal)
    const void* __restrict__ wc,                  // [65536,256] external
    const void* __restrict__ bc,                  // [65536]     external
    const unsigned short* __restrict__ ip,        // [2048,256] bf16 (internal)
    const int* __restrict__ flagp,
    float* __restrict__ outT)                     // [256 i][2048 m] f32 (ws)
{
    extern __shared__ __align__(16) unsigned char lds[];
    unsigned short* Bs = (unsigned short*)lds;              // 131072 B
    unsigned short* As = (unsigned short*)(lds + 131072);   // 32768 B
    float*          part = (float*)(lds + 131072);          // overlay [2][256]

    const int isf32 = *flagp;
    const int tid  = threadIdx.x;
    const int lane = tid & 63;
    const int wave = tid >> 6;        // 0..7
    const int i    = blockIdx.x;      // 0..255
    const int mh   = wave & 3;        // m-subblock (64 rows)
    const int jh   = wave >> 2;       // j-half (128 cols)
    const int l31  = lane & 31;
    const int lhi  = lane >> 5;

    // per-lane bc values for this lane's accumulator columns
    float bcv[4];
#pragma unroll
    for (int n = 0; n < 4; ++n)
        bcv[n] = load1(bc, i*HH + jh*128 + n*32 + l31, isf32);

    // ---- stage B once: 256 rows x 256 k, fp32/bf16 -> bf16, swizzled ----
#pragma unroll
    for (int p = 0; p < 16; ++p) {
        int u = tid + p*512;
        int row = u >> 5, cu = u & 31;
        F8 f = load8(wc, (i*HH + row)*HH + cu*8, isf32);
        unsigned short tmp[8];
#pragma unroll
        for (int j = 0; j < 8; ++j) tmp[j] = f2bf(f.v[j]);
        *(uint4*)(Bs + row*256 + ((cu ^ (row & 7)) << 3)) = *(const uint4*)tmp;
    }
    // first kc's barrier covers B visibility

    // prefetch A(mc=0, kc=0)
    uint4 areg[4];
#pragma unroll
    for (int p = 0; p < 4; ++p) {
        int u = tid + p*512;
        int row = u >> 3, cu = u & 7;
        areg[p] = *(const uint4*)(ctx_hist + row*HH + cu*8);
    }

    for (int mc = 0; mc < 8; ++mc) {
        const int m0 = mc * 256;

        f32x16 acc[2][4];
#pragma unroll
        for (int a = 0; a < 2; ++a)
#pragma unroll
            for (int n = 0; n < 4; ++n)
#pragma unroll
                for (int r = 0; r < 16; ++r) acc[a][n][r] = 0.0f;

#pragma unroll
        for (int kc = 0; kc < 4; ++kc) {
            __syncthreads();   // prior LDS reads (MFMA or partial) complete
            // write current A chunk from regs
#pragma unroll
            for (int p = 0; p < 4; ++p) {
                int u = tid + p*512;
                int row = u >> 3, cu = u & 7;
                *(uint4*)(As + row*64 + ((cu ^ (row & 7)) << 3)) = areg[p];
            }
            __syncthreads();
            // prefetch next A chunk (hidden behind the MFMA loop)
            {
                int nmc = mc, nkc = kc + 1;
                if (nkc == 4) { nkc = 0; nmc = mc + 1; }
                if (nmc < 8) {
                    const unsigned short* src = ctx_hist + (nmc*256)*HH + nkc*64;
#pragma unroll
                    for (int p = 0; p < 4; ++p) {
                        int u = tid + p*512;
                        int row = u >> 3, cu = u & 7;
                        areg[p] = *(const uint4*)(src + row*HH + cu*8);
                    }
                }
            }
#pragma unroll
            for (int ks = 0; ks < 4; ++ks) {
                const int cA = ks*2 + lhi;          // 0..7
                const int ra0 = mh*64 + l31;
                const int ra1 = ra0 + 32;
                bf16x8 a0 = *(const bf16x8*)(As + ra0*64 + ((cA ^ (ra0 & 7)) << 3));
                bf16x8 a1 = *(const bf16x8*)(As + ra1*64 + ((cA ^ (ra1 & 7)) << 3));
                const int cB = kc*8 + ks*2 + lhi;   // 0..31
                const int rb0 = jh*128 +       l31;
                const int rb1 = jh*128 + 32  + l31;
                const int rb2 = jh*128 + 64  + l31;
                const int rb3 = jh*128 + 96  + l31;
                bf16x8 b0 = *(const bf16x8*)(Bs + rb0*256 + ((cB ^ (rb0 & 7)) << 3));
                bf16x8 b1 = *(const bf16x8*)(Bs + rb1*256 + ((cB ^ (rb1 & 7)) << 3));
                bf16x8 b2 = *(const bf16x8*)(Bs + rb2*256 + ((cB ^ (rb2 & 7)) << 3));
                bf16x8 b3 = *(const bf16x8*)(Bs + rb3*256 + ((cB ^ (rb3 & 7)) << 3));
                acc[0][0] = __builtin_amdgcn_mfma_f32_32x32x16_bf16(a0, b0, acc[0][0], 0, 0, 0);
                acc[0][1] = __builtin_amdgcn_mfma_f32_32x32x16_bf16(a0, b1, acc[0][1], 0, 0, 0);
                acc[0][2] = __builtin_amdgcn_mfma_f32_32x32x16_bf16(a0, b2, acc[0][2], 0, 0, 0);
                acc[0][3] = __builtin_amdgcn_mfma_f32_32x32x16_bf16(a0, b3, acc[0][3], 0, 0, 0);
                acc[1][0] = __builtin_amdgcn_mfma_f32_32x32x16_bf16(a1, b0, acc[1][0], 0, 0, 0);
                acc[1][1] = __builtin_amdgcn_mfma_f32_32x32x16_bf16(a1, b1, acc[1][1], 0, 0, 0);
                acc[1][2] = __builtin_amdgcn_mfma_f32_32x32x16_bf16(a1, b2, acc[1][2], 0, 0, 0);
                acc[1][3] = __builtin_amdgcn_mfma_f32_32x32x16_bf16(a1, b3, acc[1][3], 0, 0, 0);
            }
        }

        // ---- epilogue: in-register reduction over j, shfl + tiny LDS merge
        __syncthreads();   // MFMA LDS reads done; As region reusable as `part`
#pragma unroll
        for (int a = 0; a < 2; ++a) {
#pragma unroll
            for (int r = 0; r < 16; ++r) {
                const int rl = (r & 3) + 8*(r >> 2) + 4*lhi;   // 0..31
                const int gm = m0 + mh*64 + a*32 + rl;
                const unsigned short* ipr = ip + gm*HH + jh*128 + l31;
                float p = 0.0f;
#pragma unroll
                for (int n = 0; n < 4; ++n)
                    p = fmaf(acc[a][n][r] + bcv[n], bf2f(ipr[n*32]), p);
                p += __shfl_xor(p, 1);
                p += __shfl_xor(p, 2);
                p += __shfl_xor(p, 4);
                p += __shfl_xor(p, 8);
                p += __shfl_xor(p, 16);
                if (l31 == rl) part[jh*256 + mh*64 + a*32 + rl] = p;
            }
        }
        __syncthreads();
        if (tid < 256)
            outT[(size_t)i*MM + m0 + tid] = part[tid] + part[256 + tid];
        // next kc-loop-top barrier protects `part` before As is rewritten
    }
}

// ---------------------------------------------------------------------------
// K4: transpose outT[256 i][2048 m] f32 -> out[m][i] (+ final-hidden chunk).
// Grid (32 m-tiles, 4 i-tiles), 256 threads, 64x64 tiles, padded LDS.
// ---------------------------------------------------------------------------
__global__ __launch_bounds__(256) void k4_tr(
    const float* __restrict__ outT,
    const int* __restrict__ flagp,
    void* __restrict__ out)
{
    const int isf32 = *flagp;
    __shared__ float tile[64][65];
    const int m0 = blockIdx.x * 64, i0 = blockIdx.y * 64;
    const int tm = threadIdx.x & 63, tq = threadIdx.x >> 6;   // tq 0..3
#pragma unroll
    for (int rep = 0; rep < 16; ++rep) {
        int il = tq + rep*4;
        tile[il][tm] = outT[(size_t)(i0 + il)*MM + m0 + tm];
    }
    __syncthreads();
#pragma unroll
    for (int rep = 0; rep < 16; ++rep) {
        int ml = tq + rep*4;
        int ii = tm;
        float v = tile[ii][ml];
        int mg = m0 + ml, ig = i0 + ii;
        if (isf32) {
            float* o = (float*)out;
            o[(size_t)mg*HH + ig] = v;
            if (mg >= MM - BB) o[(size_t)MM*HH + (mg - (MM-BB))*HH + ig] = v;
        } else {
            unsigned short* o = (unsigned short*)out;
            unsigned short b = f2bf(v);
            o[(size_t)mg*HH + ig] = b;
            if (mg >= MM - BB) o[(size_t)MM*HH + (mg - (MM-BB))*HH + ig] = b;
        }
    }
}

// ---------------------------------------------------------------------------
extern "C" void kernel_launch(void* const* d_in, const int* in_sizes, int n_in,
                              void* d_out, int out_size, void* d_ws, size_t ws_size,
                              hipStream_t stream) {
    const void* x     = d_in[0];
    const void* w_i2h = d_in[1];
    const void* b_i2h = d_in[2];
    // d_in[3]=w_h2h, d_in[4]=b_h2h: dead code (reference overwrites hidden=transformed)
    const void* w_i2c = d_in[5];
    const void* b_i2c = d_in[6];
    const void* w_c2c = d_in[7];
    const void* b_c2c = d_in[8];
    const void* w_c2t = d_in[9];
    const void* b_c2t = d_in[10];
    const int* ns     = (const int*)d_in[11];

    // ws layout: ip bf16 [2048,256] | ctx_hist bf16 | cin f32 | flag | outT f32
    unsigned short* ip  = (unsigned short*)d_ws;
    unsigned short* ch  = (unsigned short*)((char*)d_ws + (size_t)MM*HH*2);
    float* cin          = (float*)((char*)d_ws + (size_t)MM*HH*4);
    int* flag           = (int*)((char*)d_ws + (size_t)MM*HH*8);
    float* outT         = (float*)((char*)d_ws + (size_t)MM*HH*8 + 1024);

    // allow 160 KiB dynamic LDS for k3 (host-side attribute; capture-safe)
    (void)hipFuncSetAttribute((const void*)k3_main,
                              hipFuncAttributeMaxDynamicSharedMemorySize, 163840);

    k0_sniff<<<1, 256, 0, stream>>>((const unsigned short*)x, flag);
    k1_proj<<<64, 256, 0, stream>>>(x, w_i2h, b_i2h, w_i2c, b_i2c, flag, ip, cin);
    k2_ctx<<<BB, 256, 0, stream>>>(w_c2c, b_c2c, cin, ns, flag, ch, d_out);
    k3_main<<<256, 512, 163840, stream>>>(ch, w_c2t, b_c2t, ip, flag, outT);
    k4_tr<<<dim3(32, 4), 256, 0, stream>>>(outT, flag, d_out);
}